// Round 15
// baseline (4506.955 us; speedup 1.0000x reference)
//
#include <hip/hip_runtime.h>

#define TPB 256
#define RBITS 10               // bucket = node >> 10 (1024 nodes/bucket)
#define RSZ   1024
#define BMAX  512              // max buckets supported (N <= 512K)
#define CHUNK 4096             // edges per block-iteration in bucket passes
constexpr float EPSV = 1e-5f;

__device__ __forceinline__ float bf2f(unsigned short u) {
  return __uint_as_float((unsigned)u << 16);
}
__device__ __forceinline__ unsigned short f2bf(float f) {
  unsigned u = __float_as_uint(f);
  return (unsigned short)((u + 0x7fffu + ((u >> 16) & 1u)) >> 16);  // RNE
}

// ---- shared-memory union: one static block reused per phase (max 13.3 KB) ----
union SMem {
  struct { int h[BMAX]; } bc;
  struct { int red[BMAX]; } bs;
  struct { int h[BMAX]; int base[BMAX]; int cur[BMAX]; } bf;
  struct { int cnt[RSZ]; float wsum[RSZ]; int lofs[RSZ]; int red[256]; } bk;
  struct { float Ws[224]; float hs[32 * 9]; } t0;
  struct { float Ws[1024]; float hs[32 * 33]; float ssb[64]; } tr;
  struct { float ls[64]; } st;
  struct { float red[64 * 33]; } pl;
  struct { float Ws[1024]; float ps[256]; float ls[256]; float lq[256]; } mz;
  struct { float sc[32]; float sh[32]; float w1[64]; } mf;
};

// ---- device-scope grid barrier (generation counter). Co-residency is
// guaranteed: __launch_bounds__(256,4) + grid = 4 * CU count. cnt/gen are
// zeroed by the pre-launch memset. ----
__device__ __forceinline__ void gsync(unsigned* cnt, unsigned* gen) {
  __syncthreads();
  if (threadIdx.x == 0) {
    __threadfence();
    unsigned g = __hip_atomic_load(gen, __ATOMIC_ACQUIRE, __HIP_MEMORY_SCOPE_AGENT);
    unsigned a = __hip_atomic_fetch_add(cnt, 1u, __ATOMIC_ACQ_REL, __HIP_MEMORY_SCOPE_AGENT);
    if (a == gridDim.x - 1) {
      __hip_atomic_store(cnt, 0u, __ATOMIC_RELAXED, __HIP_MEMORY_SCOPE_AGENT);
      __hip_atomic_fetch_add(gen, 1u, __ATOMIC_ACQ_REL, __HIP_MEMORY_SCOPE_AGENT);
    } else {
      while (__hip_atomic_load(gen, __ATOMIC_ACQUIRE, __HIP_MEMORY_SCOPE_AGENT) == g) {
        __builtin_amdgcn_s_sleep(8);
      }
    }
    __threadfence();
  }
  __syncthreads();
}

struct GP {
  const int* row; const int* col; const float* ea; const float* x; const int* batch;
  const float* W0; const float* W1; const float* W2; const float* W3; const float* b3;
  const float* bng; const float* bnb;
  const float* Wm0; const float* bm0; const float* bnmg; const float* bnmb;
  const float* Wm1; const float* bm1;
  int* bcnt; int* bbase; int* bcur; int* ptr;
  uint2* buck; uint2* pk; float* dinv;
  uint4* G0; uint4* G1; uint4* BA; uint4* BB;
  float* stats; float* pool; float* zbuf;
  unsigned* cnt; unsigned* gen;
  float* outp;
  int N, E, B, nchunks;
  float invN;
};

// ---- gather phase (r13 lane-per-node form, verbatim body, grid-stride) ----
__device__ __forceinline__ void fma8(float* acc, uint4 v, float wt) {
  acc[0] += wt * __uint_as_float(v.x << 16);
  acc[1] += wt * __uint_as_float(v.x & 0xffff0000u);
  acc[2] += wt * __uint_as_float(v.y << 16);
  acc[3] += wt * __uint_as_float(v.y & 0xffff0000u);
  acc[4] += wt * __uint_as_float(v.z << 16);
  acc[5] += wt * __uint_as_float(v.z & 0xffff0000u);
  acc[6] += wt * __uint_as_float(v.w << 16);
  acc[7] += wt * __uint_as_float(v.w & 0xffff0000u);
}

template <int Q>
__device__ void gather_phase(const uint2* __restrict__ pk, const int* __restrict__ ptr,
                             const float* __restrict__ dinv, const uint4* __restrict__ t4,
                             uint4* __restrict__ out4, int N) {
  for (int n = blockIdx.x * TPB + threadIdx.x; n < N; n += gridDim.x * TPB) {
    const int p0 = ptr[n], p1 = ptr[n + 1];
    const float dvn = dinv[n];
    float acc[8 * Q];
#pragma unroll
    for (int k = 0; k < 8 * Q; ++k) acc[k] = 0.f;
    {
      const float wt = dvn * dvn;
      const size_t rb = (size_t)n * Q;
#pragma unroll
      for (int qq = 0; qq < Q; ++qq) fma8(acc + 8 * qq, t4[rb + qq], wt);
    }
    if (p0 < p1) {
      uint2 e = pk[p0];
      for (int p = p0; p < p1; ++p) {
        uint2 en = pk[p + 1];  // prefetch (pk allocated E+1)
        const float wt = __uint_as_float(e.y);
        const size_t rb = (size_t)e.x * Q;
#pragma unroll
        for (int qq = 0; qq < Q; ++qq) fma8(acc + 8 * qq, t4[rb + qq], wt);
        e = en;
      }
    }
    const size_t ob = (size_t)n * Q;
#pragma unroll
    for (int qq = 0; qq < Q; ++qq) {
      uint4 o;
      o.x = (unsigned)f2bf(acc[qq * 8 + 0]) | ((unsigned)f2bf(acc[qq * 8 + 1]) << 16);
      o.y = (unsigned)f2bf(acc[qq * 8 + 2]) | ((unsigned)f2bf(acc[qq * 8 + 3]) << 16);
      o.z = (unsigned)f2bf(acc[qq * 8 + 4]) | ((unsigned)f2bf(acc[qq * 8 + 5]) << 16);
      o.w = (unsigned)f2bf(acc[qq * 8 + 6]) | ((unsigned)f2bf(acc[qq * 8 + 7]) << 16);
      out4[ob + qq] = o;
    }
  }
}

// ---- transform phase (r13 split form, grid-stride over 32-node tiles) ----
__device__ void transform_phase(const uint4* __restrict__ in4, const float* __restrict__ W,
                                const float* __restrict__ gstats, const float* __restrict__ gamma,
                                const float* __restrict__ beta, float invN,
                                uint2* __restrict__ t2, int N, SMem* sm) {
  float* Ws = sm->tr.Ws;
  float* hs = sm->tr.hs;
  float* ssb = sm->tr.ssb;
  const int tid = threadIdx.x;
#pragma unroll
  for (int k = 0; k < 4; ++k) Ws[k * 256 + tid] = W[k * 256 + tid];
  if (tid < 32) {
    float m = gstats[tid] * invN;
    float v = gstats[32 + tid] * invN - m * m;
    float s = gamma[tid] * rsqrtf(v + EPSV);
    ssb[tid] = s;
    ssb[32 + tid] = beta[tid] - m * s;
  }
  __syncthreads();
  const int ntiles = (N + 31) / 32;
  for (int t = blockIdx.x; t < ntiles; t += gridDim.x) {
    const int n0 = t * 32;
    if (tid < 128) {
      const int r = tid >> 2, q = tid & 3;
      const int node = n0 + r;
      uint4 v = make_uint4(0, 0, 0, 0);
      if (node < N) v = in4[(size_t)node * 4 + q];
      float* h = &hs[r * 33 + q * 8];
      const float* sc = &ssb[q * 8];
      const float* sh = &ssb[32 + q * 8];
      h[0] = fmaxf(__uint_as_float(v.x << 16) * sc[0] + sh[0], 0.f);
      h[1] = fmaxf(__uint_as_float(v.x & 0xffff0000u) * sc[1] + sh[1], 0.f);
      h[2] = fmaxf(__uint_as_float(v.y << 16) * sc[2] + sh[2], 0.f);
      h[3] = fmaxf(__uint_as_float(v.y & 0xffff0000u) * sc[3] + sh[3], 0.f);
      h[4] = fmaxf(__uint_as_float(v.z << 16) * sc[4] + sh[4], 0.f);
      h[5] = fmaxf(__uint_as_float(v.z & 0xffff0000u) * sc[5] + sh[5], 0.f);
      h[6] = fmaxf(__uint_as_float(v.w << 16) * sc[6] + sh[6], 0.f);
      h[7] = fmaxf(__uint_as_float(v.w & 0xffff0000u) * sc[7] + sh[7], 0.f);
    }
    __syncthreads();
    const int j = tid >> 3;
    const int c0 = (tid & 7) * 4;
    const int node = n0 + j;
    if (node < N) {
      float a0 = 0.f, a1 = 0.f, a2 = 0.f, a3 = 0.f;
#pragma unroll
      for (int k = 0; k < 32; ++k) {
        float v = hs[j * 33 + k];
        const float* w = &Ws[k * 32 + c0];
        a0 += v * w[0]; a1 += v * w[1]; a2 += v * w[2]; a3 += v * w[3];
      }
      uint2 o;
      o.x = (unsigned)f2bf(a0) | ((unsigned)f2bf(a1) << 16);
      o.y = (unsigned)f2bf(a2) | ((unsigned)f2bf(a3) << 16);
      t2[(size_t)node * 8 + (tid & 7)] = o;
    }
    __syncthreads();
  }
}

// ---- stats phase (r13 vectorized form) ----
__device__ void stats_phase(const uint4* __restrict__ x4, float* __restrict__ gstats,
                            int nquads, SMem* sm) {
  float* ls = sm->st.ls;
  const int tid = threadIdx.x;
  if (tid < 64) ls[tid] = 0.f;
  __syncthreads();
  const int q = tid & 3;
  float s[8], sq[8];
#pragma unroll
  for (int k = 0; k < 8; ++k) { s[k] = 0.f; sq[k] = 0.f; }
  for (int idx = blockIdx.x * TPB + tid; idx < nquads; idx += gridDim.x * TPB) {
    uint4 v = x4[idx];
    float f0 = __uint_as_float(v.x << 16), f1 = __uint_as_float(v.x & 0xffff0000u);
    float f2 = __uint_as_float(v.y << 16), f3 = __uint_as_float(v.y & 0xffff0000u);
    float f4 = __uint_as_float(v.z << 16), f5 = __uint_as_float(v.z & 0xffff0000u);
    float f6 = __uint_as_float(v.w << 16), f7 = __uint_as_float(v.w & 0xffff0000u);
    s[0] += f0; sq[0] += f0 * f0;  s[1] += f1; sq[1] += f1 * f1;
    s[2] += f2; sq[2] += f2 * f2;  s[3] += f3; sq[3] += f3 * f3;
    s[4] += f4; sq[4] += f4 * f4;  s[5] += f5; sq[5] += f5 * f5;
    s[6] += f6; sq[6] += f6 * f6;  s[7] += f7; sq[7] += f7 * f7;
  }
#pragma unroll
  for (int k = 0; k < 8; ++k) {
    int c = q * 8 + k;
    atomicAdd(&ls[c], s[k]);
    atomicAdd(&ls[32 + c], sq[k]);
  }
  __syncthreads();
  if (tid < 64) unsafeAtomicAdd(&gstats[tid], ls[tid]);
}

// =================== the mega-kernel: entire pipeline, 18 grid barriers ===================

__global__ __launch_bounds__(256, 4) void k_mega(GP p) {
  __shared__ SMem sm;
  const int tid = threadIdx.x;

  // ---- phase 0: packx + bucket histogram ----
  for (int n = blockIdx.x * TPB + tid; n < p.N; n += gridDim.x * TPB) {
    const float* px = p.x + (size_t)n * 7;
    unsigned b[8];
#pragma unroll
    for (int k = 0; k < 7; ++k) b[k] = f2bf(px[k]);
    b[7] = 0;
    uint4 o;
    o.x = b[0] | (b[1] << 16); o.y = b[2] | (b[3] << 16);
    o.z = b[4] | (b[5] << 16); o.w = b[6] | (b[7] << 16);
    p.G0[n] = o;
  }
  for (int ch = blockIdx.x; ch < p.nchunks; ch += gridDim.x) {
    for (int i = tid; i < p.B; i += TPB) sm.bc.h[i] = 0;
    __syncthreads();
    const int e0 = ch * CHUNK;
    for (int k = tid; k < CHUNK; k += TPB) {
      int i = e0 + k;
      if (i < p.E) atomicAdd(&sm.bc.h[p.col[i] >> RBITS], 1);
    }
    __syncthreads();
    for (int i = tid; i < p.B; i += TPB)
      if (sm.bc.h[i]) atomicAdd(&p.bcnt[i], sm.bc.h[i]);
    __syncthreads();
  }
  gsync(p.cnt, p.gen);  // 1

  // ---- phase 1: bucket scan (block 0, 256 threads x 2 elems) ----
  if (blockIdx.x == 0) {
    int v0 = (2 * tid < p.B) ? p.bcnt[2 * tid] : 0;
    int v1 = (2 * tid + 1 < p.B) ? p.bcnt[2 * tid + 1] : 0;
    sm.bs.red[tid] = v0 + v1;
    __syncthreads();
    for (int off = 1; off < 256; off <<= 1) {
      int u = (tid >= off) ? sm.bs.red[tid - off] : 0;
      __syncthreads();
      sm.bs.red[tid] += u;
      __syncthreads();
    }
    int excl = sm.bs.red[tid] - (v0 + v1);
    if (2 * tid < p.B)     { p.bbase[2 * tid] = excl;      p.bcur[2 * tid] = excl; }
    if (2 * tid + 1 < p.B) { p.bbase[2 * tid + 1] = excl + v0; p.bcur[2 * tid + 1] = excl + v0; }
    if (tid == 0) p.bbase[p.B] = p.E;
  }
  gsync(p.cnt, p.gen);  // 2

  // ---- phase 2: bin edges into bucket-grouped runs ----
  for (int ch = blockIdx.x; ch < p.nchunks; ch += gridDim.x) {
    for (int i = tid; i < p.B; i += TPB) { sm.bf.h[i] = 0; sm.bf.cur[i] = 0; }
    __syncthreads();
    const int e0 = ch * CHUNK;
    for (int k = tid; k < CHUNK; k += TPB) {
      int i = e0 + k;
      if (i < p.E) atomicAdd(&sm.bf.h[p.col[i] >> RBITS], 1);
    }
    __syncthreads();
    for (int i = tid; i < p.B; i += TPB)
      sm.bf.base[i] = sm.bf.h[i] ? atomicAdd(&p.bcur[i], sm.bf.h[i]) : 0;
    __syncthreads();
    for (int k = tid; k < CHUNK; k += TPB) {
      int i = e0 + k;
      if (i >= p.E) continue;
      int c = p.col[i];
      int b = c >> RBITS;
      int pos = sm.bf.base[b] + atomicAdd(&sm.bf.cur[b], 1);
      unsigned lc = (unsigned)(c & (RSZ - 1));
      p.buck[pos] = make_uint2((unsigned)p.row[i] | (lc << 19), __float_as_uint(p.ea[i]));
    }
    __syncthreads();
  }
  gsync(p.cnt, p.gen);  // 3

  // ---- phase 3: per-bucket counting sort -> CSR + dinv; pk.y = w*dinv[col] ----
  if (blockIdx.x == 0 && tid == 0) p.ptr[p.N] = p.E;
  for (int bk = blockIdx.x; bk < p.B; bk += gridDim.x) {
    const int n0 = bk << RBITS;
    const int nloc = min(RSZ, p.N - n0);
    for (int i = tid; i < RSZ; i += 256) { sm.bk.cnt[i] = 0; sm.bk.wsum[i] = 0.f; }
    __syncthreads();
    const int e0 = p.bbase[bk], e1 = p.bbase[bk + 1];
    for (int i = e0 + tid; i < e1; i += 256) {
      uint2 e = p.buck[i];
      int lc = e.x >> 19;
      atomicAdd(&sm.bk.cnt[lc], 1);
      atomicAdd(&sm.bk.wsum[lc], __uint_as_float(e.y));
    }
    __syncthreads();
    int a = sm.bk.cnt[tid * 4], b = sm.bk.cnt[tid * 4 + 1];
    int c = sm.bk.cnt[tid * 4 + 2], d = sm.bk.cnt[tid * 4 + 3];
    int l1 = a, l2 = a + b, l3 = a + b + c, s = a + b + c + d;
    sm.bk.red[tid] = s;
    __syncthreads();
    for (int off = 1; off < 256; off <<= 1) {
      int u = (tid >= off) ? sm.bk.red[tid - off] : 0;
      __syncthreads();
      sm.bk.red[tid] += u;
      __syncthreads();
    }
    int tb = sm.bk.red[tid] - s;
    sm.bk.lofs[tid * 4] = tb;     sm.bk.lofs[tid * 4 + 1] = tb + l1;
    sm.bk.lofs[tid * 4 + 2] = tb + l2; sm.bk.lofs[tid * 4 + 3] = tb + l3;
    __syncthreads();
    for (int i = tid; i < nloc; i += 256) {
      p.ptr[n0 + i] = e0 + sm.bk.lofs[i];
      p.dinv[n0 + i] = rsqrtf(1.0f + sm.bk.wsum[i]);
    }
    for (int i = tid; i < RSZ; i += 256) sm.bk.cnt[i] = 0;
    __syncthreads();
    for (int i = e0 + tid; i < e1; i += 256) {
      uint2 e = p.buck[i];
      int lc = e.x >> 19;
      int pos = e0 + sm.bk.lofs[lc] + atomicAdd(&sm.bk.cnt[lc], 1);
      float wdc = __uint_as_float(e.y) * rsqrtf(1.0f + sm.bk.wsum[lc]);
      p.pk[pos] = make_uint2(e.x & 524287u, __float_as_uint(wdc));
    }
    __syncthreads();
  }
  gsync(p.cnt, p.gen);  // 4

  // ---- phase 4: pk.y *= dinv[row] ----
  for (int e = blockIdx.x * TPB + tid; e < p.E; e += gridDim.x * TPB) {
    uint2 v = p.pk[e];
    p.pk[e].y = __float_as_uint(__uint_as_float(v.y) * p.dinv[v.x]);
  }
  gsync(p.cnt, p.gen);  // 5

  // ---- layer 0: gather raw x (16 B rows, L2-hot) ----
  gather_phase<1>(p.pk, p.ptr, p.dinv, p.G0, p.G1, p.N);
  gsync(p.cnt, p.gen);  // 6

  // ---- layer 0 transform: BA = G1 @ W0 (7 eff. channels) ----
  {
    if (tid < 224) sm.t0.Ws[tid] = p.W0[tid];
    __syncthreads();
    const int ntiles = (p.N + 31) / 32;
    for (int t = blockIdx.x; t < ntiles; t += gridDim.x) {
      const int n0 = t * 32;
      if (tid < 32) {
        const int node = n0 + tid;
        uint4 v = make_uint4(0, 0, 0, 0);
        if (node < p.N) v = p.G1[node];
        float* h = &sm.t0.hs[tid * 9];
        h[0] = __uint_as_float(v.x << 16); h[1] = __uint_as_float(v.x & 0xffff0000u);
        h[2] = __uint_as_float(v.y << 16); h[3] = __uint_as_float(v.y & 0xffff0000u);
        h[4] = __uint_as_float(v.z << 16); h[5] = __uint_as_float(v.z & 0xffff0000u);
        h[6] = __uint_as_float(v.w << 16); h[7] = 0.f;
      }
      __syncthreads();
      const int j = tid >> 3, q = tid & 7, c0 = q * 4;
      const int node = n0 + j;
      if (node < p.N) {
        float a0 = 0.f, a1 = 0.f, a2 = 0.f, a3 = 0.f;
#pragma unroll
        for (int k = 0; k < 7; ++k) {
          float v = sm.t0.hs[j * 9 + k];
          const float* w = &sm.t0.Ws[k * 32 + c0];
          a0 += v * w[0]; a1 += v * w[1]; a2 += v * w[2]; a3 += v * w[3];
        }
        uint2 o;
        o.x = (unsigned)f2bf(a0) | ((unsigned)f2bf(a1) << 16);
        o.y = (unsigned)f2bf(a2) | ((unsigned)f2bf(a3) << 16);
        ((uint2*)p.BA)[(size_t)node * 8 + q] = o;
      }
      __syncthreads();
    }
  }
  gsync(p.cnt, p.gen);  // 7
  stats_phase(p.BA, p.stats, p.N * 4, &sm);
  gsync(p.cnt, p.gen);  // 8

  // ---- layer 1 ----
  transform_phase(p.BA, p.W1, p.stats, p.bng, p.bnb, p.invN, (uint2*)p.BB, p.N, &sm);
  gsync(p.cnt, p.gen);  // 9
  gather_phase<4>(p.pk, p.ptr, p.dinv, p.BB, p.BA, p.N);
  gsync(p.cnt, p.gen);  // 10
  stats_phase(p.BA, p.stats + 64, p.N * 4, &sm);
  gsync(p.cnt, p.gen);  // 11

  // ---- layer 2 ----
  transform_phase(p.BA, p.W2, p.stats + 64, p.bng + 32, p.bnb + 32, p.invN, (uint2*)p.BB, p.N, &sm);
  gsync(p.cnt, p.gen);  // 12
  gather_phase<4>(p.pk, p.ptr, p.dinv, p.BB, p.BA, p.N);
  gsync(p.cnt, p.gen);  // 13
  stats_phase(p.BA, p.stats + 128, p.N * 4, &sm);
  gsync(p.cnt, p.gen);  // 14

  // ---- layer 3 (no BN on output) ----
  transform_phase(p.BA, p.W3, p.stats + 128, p.bng + 64, p.bnb + 64, p.invN, (uint2*)p.BB, p.N, &sm);
  gsync(p.cnt, p.gen);  // 15
  gather_phase<4>(p.pk, p.ptr, p.dinv, p.BB, p.BA, p.N);
  gsync(p.cnt, p.gen);  // 16

  // ---- pool (batch sorted; one block per graph, grid-stride) ----
  for (int g = blockIdx.x; g < 512; g += gridDim.x) {
    int lo = 0, hi = p.N;
    while (lo < hi) { int mid = (lo + hi) >> 1; if (p.batch[mid] < g) lo = mid + 1; else hi = mid; }
    const int start = lo;
    hi = p.N;
    while (lo < hi) { int mid = (lo + hi) >> 1; if (p.batch[mid] < g + 1) lo = mid + 1; else hi = mid; }
    const int end = lo;
    const int j = tid >> 2, q = tid & 3;
    float a[8];
#pragma unroll
    for (int k = 0; k < 8; ++k) a[k] = 0.f;
    for (int i = start + j; i < end; i += 64) {
      uint4 v = p.BA[(size_t)i * 4 + q];
      a[0] += __uint_as_float(v.x << 16); a[1] += __uint_as_float(v.x & 0xffff0000u);
      a[2] += __uint_as_float(v.y << 16); a[3] += __uint_as_float(v.y & 0xffff0000u);
      a[4] += __uint_as_float(v.z << 16); a[5] += __uint_as_float(v.z & 0xffff0000u);
      a[6] += __uint_as_float(v.w << 16); a[7] += __uint_as_float(v.w & 0xffff0000u);
    }
#pragma unroll
    for (int k = 0; k < 8; ++k) sm.pl.red[j * 33 + q * 8 + k] = a[k];
    __syncthreads();
    for (int off = 32; off >= 1; off >>= 1) {
      if (j < off) {
#pragma unroll
        for (int k = 0; k < 8; ++k)
          sm.pl.red[j * 33 + q * 8 + k] += sm.pl.red[(j + off) * 33 + q * 8 + k];
      }
      __syncthreads();
    }
    if (tid < 32) p.pool[g * 32 + tid] = sm.pl.red[tid] + (float)(end - start) * p.b3[tid];
    __syncthreads();
  }
  gsync(p.cnt, p.gen);  // 17

  // ---- MLP z + stats (blocks 0..63) ----
  if (blockIdx.x < 64) {
    const int g0 = blockIdx.x * 8;
    for (int k = tid; k < 1024; k += TPB) sm.mz.Ws[k] = p.Wm0[k];
    sm.mz.ps[tid] = p.pool[g0 * 32 + tid];
    __syncthreads();
    const int j = tid >> 5, c = tid & 31;
    float acc = p.bm0[c];
#pragma unroll
    for (int k = 0; k < 32; ++k) acc += sm.mz.ps[j * 32 + k] * sm.mz.Ws[k * 32 + c];
    p.zbuf[(g0 + j) * 32 + c] = acc;
    sm.mz.ls[tid] = acc;
    sm.mz.lq[tid] = acc * acc;
    __syncthreads();
    for (int off = 128; off >= 32; off >>= 1) {
      if (tid < off) { sm.mz.ls[tid] += sm.mz.ls[tid + off]; sm.mz.lq[tid] += sm.mz.lq[tid + off]; }
      __syncthreads();
    }
    if (tid < 32) {
      unsafeAtomicAdd(&p.stats[192 + tid], sm.mz.ls[tid]);
      unsafeAtomicAdd(&p.stats[192 + 32 + tid], sm.mz.lq[tid]);
    }
  }
  gsync(p.cnt, p.gen);  // 18

  // ---- MLP finalize (blocks 0..3 cover 512 graphs x 2 outputs) ----
  if (blockIdx.x < 4) {
    if (tid < 32) {
      float m = p.stats[192 + tid] * (1.0f / 512.0f);
      float v = p.stats[192 + 32 + tid] * (1.0f / 512.0f) - m * m;
      float s = p.bnmg[tid] * rsqrtf(v + EPSV);
      sm.mf.sc[tid] = s;
      sm.mf.sh[tid] = p.bnmb[tid] - m * s;
    }
    if (tid < 64) sm.mf.w1[tid] = p.Wm1[tid];
    __syncthreads();
    const int t = blockIdx.x * 256 + tid;  // 0..1023
    const int g = t >> 1, o = t & 1;
    float acc = p.bm1[o];
#pragma unroll
    for (int c = 0; c < 32; ++c) {
      float hc = fmaxf(p.zbuf[g * 32 + c] * sm.mf.sc[c] + sm.mf.sh[c], 0.f);
      acc += hc * sm.mf.w1[c * 2 + o];
    }
    p.outp[t] = acc;
  }
}

// =================== launch ===================

extern "C" void kernel_launch(void* const* d_in, const int* in_sizes, int n_in,
                              void* d_out, int out_size, void* d_ws, size_t ws_size,
                              hipStream_t stream) {
  GP p;
  p.x     = (const float*)d_in[0];
  const int* ei = (const int*)d_in[1];
  p.ea    = (const float*)d_in[2];
  p.batch = (const int*)d_in[3];
  p.W0    = (const float*)d_in[4];
  p.W1    = (const float*)d_in[6];
  p.W2    = (const float*)d_in[8];
  p.W3    = (const float*)d_in[10];
  p.b3    = (const float*)d_in[11];
  p.bng   = (const float*)d_in[12];
  p.bnb   = (const float*)d_in[13];
  p.Wm0   = (const float*)d_in[14];
  p.bm0   = (const float*)d_in[15];
  p.bnmg  = (const float*)d_in[16];
  p.bnmb  = (const float*)d_in[17];
  p.Wm1   = (const float*)d_in[18];
  p.bm1   = (const float*)d_in[19];
  p.outp  = (float*)d_out;

  p.N = in_sizes[3];
  p.E = in_sizes[2];
  p.row = ei;
  p.col = ei + p.E;
  p.B = (p.N + RSZ - 1) >> RBITS;
  p.nchunks = (p.E + CHUNK - 1) / CHUNK;
  p.invN = 1.0f / (float)p.N;

  char* wsb = (char*)d_ws;
  auto alloc = [&](size_t bytes) { char* q = wsb; wsb += (bytes + 255) & ~size_t(255); return q; };
  // zeroed region first (one memset): cnt, gen, bcnt[BMAX+1], stats[256]
  unsigned* zbase = (unsigned*)alloc((2 + BMAX + 1 + 256) * 4);
  p.cnt   = zbase;
  p.gen   = zbase + 1;
  p.bcnt  = (int*)(zbase + 2);
  p.stats = (float*)(zbase + 2 + BMAX + 1);
  p.bbase = (int*)alloc((size_t)(BMAX + 1) * 4);
  p.bcur  = (int*)alloc((size_t)BMAX * 4);
  p.ptr   = (int*)alloc((size_t)(p.N + 1) * 4);
  p.buck  = (uint2*)alloc((size_t)p.E * 8);
  p.pk    = (uint2*)alloc((size_t)(p.E + 1) * 8);  // +1: prefetch slot
  p.dinv  = (float*)alloc((size_t)p.N * 4);
  p.G0    = (uint4*)alloc((size_t)p.N * 16);
  p.G1    = (uint4*)alloc((size_t)p.N * 16);
  p.BA    = (uint4*)alloc((size_t)p.N * 64);
  p.BB    = (uint4*)alloc((size_t)p.N * 64);
  p.pool  = (float*)alloc(512 * 32 * 4);
  p.zbuf  = (float*)alloc(512 * 32 * 4);

  hipMemsetAsync(zbase, 0, (2 + BMAX + 1 + 256) * 4, stream);

  int dev = 0, mp = 256;
  hipGetDevice(&dev);
  hipDeviceGetAttribute(&mp, hipDeviceAttributeMultiprocessorCount, dev);
  const int grid = mp * 4;  // co-resident by __launch_bounds__(256, 4)

  k_mega<<<grid, TPB, 0, stream>>>(p);
}

// Round 16
// 744.593 us; speedup vs baseline: 6.0529x; 6.0529x over previous
//
#include <hip/hip_runtime.h>

#define TPB 256
#define RBITS 10               // bucket = node >> 10 (1024 nodes/bucket)
#define RSZ   1024
#define BMAX  512              // max buckets supported (N <= 512K)
#define CHUNK 4096             // edges per block in bucket passes
constexpr float EPSV = 1e-5f;

__device__ __forceinline__ float bf2f(unsigned short u) {
  return __uint_as_float((unsigned)u << 16);
}
__device__ __forceinline__ unsigned short f2bf(float f) {
  unsigned u = __float_as_uint(f);
  return (unsigned short)((u + 0x7fffu + ((u >> 16) & 1u)) >> 16);  // RNE
}

// =================== bucket-sorted CSR build ===================

__global__ void k_bcnt(const int* __restrict__ col, int* __restrict__ bcnt,
                       const float* __restrict__ x, uint4* __restrict__ g,
                       int E, int B, int N) {
  __shared__ int h[BMAX];
  const int tid = threadIdx.x;
  for (int i = tid; i < B; i += TPB) h[i] = 0;
  __syncthreads();
  const int e0 = blockIdx.x * CHUNK;
  for (int k = tid; k < CHUNK; k += TPB) {
    int i = e0 + k;
    if (i < E) atomicAdd(&h[col[i] >> RBITS], 1);
  }
  __syncthreads();
  for (int i = tid; i < B; i += TPB)
    if (h[i]) atomicAdd(&bcnt[i], h[i]);
  // fused packx (independent work, grid-stride)
  for (int n = blockIdx.x * TPB + tid; n < N; n += gridDim.x * TPB) {
    const float* p = x + (size_t)n * 7;
    unsigned b[8];
#pragma unroll
    for (int k = 0; k < 7; ++k) b[k] = f2bf(p[k]);
    b[7] = 0;
    uint4 o;
    o.x = b[0] | (b[1] << 16); o.y = b[2] | (b[3] << 16);
    o.z = b[4] | (b[5] << 16); o.w = b[6] | (b[7] << 16);
    g[n] = o;
  }
}

__global__ void k_bscan(const int* __restrict__ bcnt, int* __restrict__ bbase,
                        int* __restrict__ bcur, int B, int E) {
  __shared__ int red[BMAX];
  const int tid = threadIdx.x;  // 512 threads
  int v = (tid < B) ? bcnt[tid] : 0;
  red[tid] = v;
  __syncthreads();
  for (int off = 1; off < BMAX; off <<= 1) {
    int u = (tid >= off) ? red[tid - off] : 0;
    __syncthreads();
    red[tid] += u;
    __syncthreads();
  }
  int excl = red[tid] - v;
  if (tid < B) { bbase[tid] = excl; bcur[tid] = excl; }
  if (tid == 0) bbase[B] = E;
}

__global__ void k_binfill(const int* __restrict__ row, const int* __restrict__ col,
                          const float* __restrict__ w, int* __restrict__ bcur,
                          uint2* __restrict__ buck, int E, int B) {
  __shared__ int h[BMAX], base[BMAX], cur[BMAX];
  const int tid = threadIdx.x;
  for (int i = tid; i < B; i += TPB) { h[i] = 0; cur[i] = 0; }
  __syncthreads();
  const int e0 = blockIdx.x * CHUNK;
  for (int k = tid; k < CHUNK; k += TPB) {
    int i = e0 + k;
    if (i < E) atomicAdd(&h[col[i] >> RBITS], 1);
  }
  __syncthreads();
  for (int i = tid; i < B; i += TPB)
    base[i] = h[i] ? atomicAdd(&bcur[i], h[i]) : 0;
  __syncthreads();
  for (int k = tid; k < CHUNK; k += TPB) {
    int i = e0 + k;
    if (i >= E) continue;
    int c = col[i];
    int b = c >> RBITS;
    int pos = base[b] + atomicAdd(&cur[b], 1);
    unsigned lc = (unsigned)(c & (RSZ - 1));
    buck[pos] = make_uint2((unsigned)row[i] | (lc << 19), __float_as_uint(w[i]));
  }
}

// per-bucket counting sort -> CSR; pk.y pre-multiplied by dinv[col] (local!)
__global__ __launch_bounds__(256) void k_bucket(const uint2* __restrict__ buck,
                                                const int* __restrict__ bbase,
                                                int* __restrict__ ptr, float* __restrict__ dinv,
                                                uint2* __restrict__ pk, int N, int E) {
  __shared__ int cnt[RSZ];
  __shared__ float wsum[RSZ];
  __shared__ int lofs[RSZ];
  __shared__ int red[256];
  const int bk = blockIdx.x, tid = threadIdx.x;
  const int n0 = bk << RBITS;
  const int nloc = min(RSZ, N - n0);
  for (int i = tid; i < RSZ; i += 256) { cnt[i] = 0; wsum[i] = 0.f; }
  __syncthreads();
  const int e0 = bbase[bk], e1 = bbase[bk + 1];
  for (int i = e0 + tid; i < e1; i += 256) {
    uint2 e = buck[i];
    int lc = e.x >> 19;
    atomicAdd(&cnt[lc], 1);
    atomicAdd(&wsum[lc], __uint_as_float(e.y));
  }
  __syncthreads();
  int a = cnt[tid * 4], b = cnt[tid * 4 + 1], c = cnt[tid * 4 + 2], d = cnt[tid * 4 + 3];
  int l1 = a, l2 = a + b, l3 = a + b + c, s = a + b + c + d;
  red[tid] = s;
  __syncthreads();
  for (int off = 1; off < 256; off <<= 1) {
    int u = (tid >= off) ? red[tid - off] : 0;
    __syncthreads();
    red[tid] += u;
    __syncthreads();
  }
  int tb = red[tid] - s;
  lofs[tid * 4] = tb; lofs[tid * 4 + 1] = tb + l1;
  lofs[tid * 4 + 2] = tb + l2; lofs[tid * 4 + 3] = tb + l3;
  __syncthreads();
  for (int i = tid; i < nloc; i += 256) {
    ptr[n0 + i] = e0 + lofs[i];
    dinv[n0 + i] = rsqrtf(1.0f + wsum[i]);  // deg >= 1 (self-loop)
  }
  for (int i = tid; i < RSZ; i += 256) cnt[i] = 0;
  __syncthreads();
  for (int i = e0 + tid; i < e1; i += 256) {
    uint2 e = buck[i];
    int lc = e.x >> 19;
    int pos = e0 + lofs[lc] + atomicAdd(&cnt[lc], 1);
    float wdc = __uint_as_float(e.y) * rsqrtf(1.0f + wsum[lc]);  // w * dinv[col]
    pk[pos] = make_uint2(e.x & 524287u, __float_as_uint(wdc));
  }
  if (bk == 0 && tid == 0) ptr[N] = E;
}

// =================== layer-0 transform: BA = G1 @ W0 (7 eff. channels) ===================

__global__ __launch_bounds__(256) void k_transform0b(
    const uint4* __restrict__ g1, const float* __restrict__ W,
    uint2* __restrict__ t2, int N) {
  __shared__ float Ws[7 * 32];
  __shared__ float hs[32 * 9];
  const int tid = threadIdx.x;
  const int n0 = blockIdx.x * 32;
  if (tid < 224) Ws[tid] = W[tid];
  if (tid < 32) {
    const int node = n0 + tid;
    uint4 v = make_uint4(0, 0, 0, 0);
    if (node < N) v = g1[node];
    float* h = &hs[tid * 9];
    h[0] = __uint_as_float(v.x << 16); h[1] = __uint_as_float(v.x & 0xffff0000u);
    h[2] = __uint_as_float(v.y << 16); h[3] = __uint_as_float(v.y & 0xffff0000u);
    h[4] = __uint_as_float(v.z << 16); h[5] = __uint_as_float(v.z & 0xffff0000u);
    h[6] = __uint_as_float(v.w << 16); h[7] = 0.f;
  }
  __syncthreads();
  const int j = tid >> 3, q = tid & 7, c0 = q * 4;
  const int node = n0 + j;
  if (node < N) {
    float a0 = 0.f, a1 = 0.f, a2 = 0.f, a3 = 0.f;
#pragma unroll
    for (int k = 0; k < 7; ++k) {
      float v = hs[j * 9 + k];
      const float* w = &Ws[k * 32 + c0];
      a0 += v * w[0]; a1 += v * w[1]; a2 += v * w[2]; a3 += v * w[3];
    }
    uint2 o;
    o.x = (unsigned)f2bf(a0) | ((unsigned)f2bf(a1) << 16);
    o.y = (unsigned)f2bf(a2) | ((unsigned)f2bf(a3) << 16);
    t2[(size_t)node * 8 + q] = o;
  }
}

// =================== transforms layers 1-3 ===================

__global__ __launch_bounds__(256) void k_transform(
    const uint4* __restrict__ in4, const float* __restrict__ W,
    const float* __restrict__ gstats, const float* __restrict__ gamma,
    const float* __restrict__ beta, float invN, uint2* __restrict__ t2, int N) {
  __shared__ float Ws[1024];
  __shared__ float hs[32 * 33];
  __shared__ float ssb[64];
  const int tid = threadIdx.x;
  const int n0 = blockIdx.x * 32;
#pragma unroll
  for (int k = 0; k < 4; ++k) Ws[k * 256 + tid] = W[k * 256 + tid];
  if (tid < 32) {
    float m = gstats[tid] * invN;
    float v = gstats[32 + tid] * invN - m * m;
    float sc = gamma[tid] * rsqrtf(v + EPSV);
    ssb[tid] = sc;
    ssb[32 + tid] = beta[tid] - m * sc;
  }
  __syncthreads();
  if (tid < 128) {
    const int r = tid >> 2, q = tid & 3;
    const int node = n0 + r;
    uint4 v = make_uint4(0, 0, 0, 0);
    if (node < N) v = in4[(size_t)node * 4 + q];
    float* h = &hs[r * 33 + q * 8];
    const float* sc = &ssb[q * 8];
    const float* sh = &ssb[32 + q * 8];
    h[0] = fmaxf(__uint_as_float(v.x << 16) * sc[0] + sh[0], 0.f);
    h[1] = fmaxf(__uint_as_float(v.x & 0xffff0000u) * sc[1] + sh[1], 0.f);
    h[2] = fmaxf(__uint_as_float(v.y << 16) * sc[2] + sh[2], 0.f);
    h[3] = fmaxf(__uint_as_float(v.y & 0xffff0000u) * sc[3] + sh[3], 0.f);
    h[4] = fmaxf(__uint_as_float(v.z << 16) * sc[4] + sh[4], 0.f);
    h[5] = fmaxf(__uint_as_float(v.z & 0xffff0000u) * sc[5] + sh[5], 0.f);
    h[6] = fmaxf(__uint_as_float(v.w << 16) * sc[6] + sh[6], 0.f);
    h[7] = fmaxf(__uint_as_float(v.w & 0xffff0000u) * sc[7] + sh[7], 0.f);
  }
  __syncthreads();
  const int j = tid >> 3;
  const int c0 = (tid & 7) * 4;
  const int node = n0 + j;
  if (node < N) {
    float a0 = 0.f, a1 = 0.f, a2 = 0.f, a3 = 0.f;
#pragma unroll
    for (int k = 0; k < 32; ++k) {
      float v = hs[j * 33 + k];
      const float* w = &Ws[k * 32 + c0];
      a0 += v * w[0]; a1 += v * w[1]; a2 += v * w[2]; a3 += v * w[3];
    }
    uint2 o;
    o.x = (unsigned)f2bf(a0) | ((unsigned)f2bf(a1) << 16);
    o.y = (unsigned)f2bf(a2) | ((unsigned)f2bf(a3) << 16);
    t2[(size_t)node * 8 + (tid & 7)] = o;
  }
}

// =================== CSR gathers: lane-per-node (r13 structure) ===================

__device__ __forceinline__ void fma8(float* acc, uint4 v, float wt) {
  acc[0] += wt * __uint_as_float(v.x << 16);
  acc[1] += wt * __uint_as_float(v.x & 0xffff0000u);
  acc[2] += wt * __uint_as_float(v.y << 16);
  acc[3] += wt * __uint_as_float(v.y & 0xffff0000u);
  acc[4] += wt * __uint_as_float(v.z << 16);
  acc[5] += wt * __uint_as_float(v.z & 0xffff0000u);
  acc[6] += wt * __uint_as_float(v.w << 16);
  acc[7] += wt * __uint_as_float(v.w & 0xffff0000u);
}

// layer 0: 16 B rows; FUSES the k_nrme pass — pk.y arrives as w*dinv[col],
// we multiply by dinv[row] (dinv is 1.6 MB -> L2-resident), use it, and
// store the final norm back for layers 1-3 (CSR ranges are lane-exclusive,
// near-sequential -> coalesced writes).
__global__ __launch_bounds__(256, 4) void k_gather0(
    uint2* __restrict__ pk, const int* __restrict__ ptr,
    const float* __restrict__ dinv, const uint4* __restrict__ t4,
    uint4* __restrict__ out4, int N) {
  const int n = blockIdx.x * 256 + threadIdx.x;
  if (n >= N) return;
  const int p0 = ptr[n], p1 = ptr[n + 1];
  const float dvn = dinv[n];
  float acc[8];
#pragma unroll
  for (int k = 0; k < 8; ++k) acc[k] = 0.f;
  fma8(acc, t4[n], dvn * dvn);
  if (p0 < p1) {
    uint2 e = pk[p0];
    for (int p = p0; p < p1; ++p) {
      uint2 en = pk[p + 1];  // prefetch (pk allocated E+1)
      const float wt = __uint_as_float(e.y) * dinv[e.x];  // finalize norm
      pk[p].y = __float_as_uint(wt);                      // store for layers 1-3
      fma8(acc, t4[e.x], wt);
      e = en;
    }
  }
  uint4 o;
  o.x = (unsigned)f2bf(acc[0]) | ((unsigned)f2bf(acc[1]) << 16);
  o.y = (unsigned)f2bf(acc[2]) | ((unsigned)f2bf(acc[3]) << 16);
  o.z = (unsigned)f2bf(acc[4]) | ((unsigned)f2bf(acc[5]) << 16);
  o.w = (unsigned)f2bf(acc[6]) | ((unsigned)f2bf(acc[7]) << 16);
  out4[n] = o;
}

// layers 1-3: 64 B rows, pk.y already final
__global__ __launch_bounds__(256, 4) void k_gather(
    const uint2* __restrict__ pk, const int* __restrict__ ptr,
    const float* __restrict__ dinv, const uint4* __restrict__ t4,
    uint4* __restrict__ out4, int N) {
  const int n = blockIdx.x * 256 + threadIdx.x;
  if (n >= N) return;
  const int p0 = ptr[n], p1 = ptr[n + 1];
  const float dvn = dinv[n];
  float acc[32];
#pragma unroll
  for (int k = 0; k < 32; ++k) acc[k] = 0.f;
  {
    const float wt = dvn * dvn;
    const size_t rb = (size_t)n * 4;
    fma8(acc, t4[rb], wt); fma8(acc + 8, t4[rb + 1], wt);
    fma8(acc + 16, t4[rb + 2], wt); fma8(acc + 24, t4[rb + 3], wt);
  }
  if (p0 < p1) {
    uint2 e = pk[p0];
    for (int p = p0; p < p1; ++p) {
      uint2 en = pk[p + 1];  // prefetch (pk allocated E+1)
      const float wt = __uint_as_float(e.y);
      const size_t rb = (size_t)e.x * 4;
      fma8(acc, t4[rb], wt); fma8(acc + 8, t4[rb + 1], wt);
      fma8(acc + 16, t4[rb + 2], wt); fma8(acc + 24, t4[rb + 3], wt);
      e = en;
    }
  }
  const size_t ob = (size_t)n * 4;
#pragma unroll
  for (int qq = 0; qq < 4; ++qq) {
    uint4 o;
    o.x = (unsigned)f2bf(acc[qq * 8 + 0]) | ((unsigned)f2bf(acc[qq * 8 + 1]) << 16);
    o.y = (unsigned)f2bf(acc[qq * 8 + 2]) | ((unsigned)f2bf(acc[qq * 8 + 3]) << 16);
    o.z = (unsigned)f2bf(acc[qq * 8 + 4]) | ((unsigned)f2bf(acc[qq * 8 + 5]) << 16);
    o.w = (unsigned)f2bf(acc[qq * 8 + 6]) | ((unsigned)f2bf(acc[qq * 8 + 7]) << 16);
    out4[ob + qq] = o;
  }
}

// =================== BN stats, vectorized (uint4 = 8 bf16 per load) ===================

__global__ void k_stats(const uint4* __restrict__ x4, float* __restrict__ gstats, int nquads) {
  __shared__ float ls[64];
  const int tid = threadIdx.x;
  if (tid < 64) ls[tid] = 0.f;
  __syncthreads();
  const int q = tid & 3;
  float s[8], sq[8];
#pragma unroll
  for (int k = 0; k < 8; ++k) { s[k] = 0.f; sq[k] = 0.f; }
  for (int idx = blockIdx.x * TPB + tid; idx < nquads; idx += gridDim.x * TPB) {
    uint4 v = x4[idx];
    float f0 = __uint_as_float(v.x << 16), f1 = __uint_as_float(v.x & 0xffff0000u);
    float f2 = __uint_as_float(v.y << 16), f3 = __uint_as_float(v.y & 0xffff0000u);
    float f4 = __uint_as_float(v.z << 16), f5 = __uint_as_float(v.z & 0xffff0000u);
    float f6 = __uint_as_float(v.w << 16), f7 = __uint_as_float(v.w & 0xffff0000u);
    s[0] += f0; sq[0] += f0 * f0;  s[1] += f1; sq[1] += f1 * f1;
    s[2] += f2; sq[2] += f2 * f2;  s[3] += f3; sq[3] += f3 * f3;
    s[4] += f4; sq[4] += f4 * f4;  s[5] += f5; sq[5] += f5 * f5;
    s[6] += f6; sq[6] += f6 * f6;  s[7] += f7; sq[7] += f7 * f7;
  }
#pragma unroll
  for (int k = 0; k < 8; ++k) {
    int c = q * 8 + k;
    atomicAdd(&ls[c], s[k]);
    atomicAdd(&ls[32 + c], sq[k]);
  }
  __syncthreads();
  if (tid < 64) unsafeAtomicAdd(&gstats[tid], ls[tid]);
}

// =================== global add pool (batch sorted, uint4 loads) ===================

__global__ __launch_bounds__(256) void k_pool(
    const uint4* __restrict__ h4, const int* __restrict__ batch,
    const float* __restrict__ b3, float* __restrict__ pool, int N) {
  __shared__ float red[64 * 33];
  const int g = blockIdx.x, tid = threadIdx.x;
  int lo = 0, hi = N;
  while (lo < hi) { int mid = (lo + hi) >> 1; if (batch[mid] < g) lo = mid + 1; else hi = mid; }
  const int start = lo;
  hi = N;
  while (lo < hi) { int mid = (lo + hi) >> 1; if (batch[mid] < g + 1) lo = mid + 1; else hi = mid; }
  const int end = lo;
  const int j = tid >> 2, q = tid & 3;
  float a[8];
#pragma unroll
  for (int k = 0; k < 8; ++k) a[k] = 0.f;
  for (int i = start + j; i < end; i += 64) {
    uint4 v = h4[(size_t)i * 4 + q];
    a[0] += __uint_as_float(v.x << 16); a[1] += __uint_as_float(v.x & 0xffff0000u);
    a[2] += __uint_as_float(v.y << 16); a[3] += __uint_as_float(v.y & 0xffff0000u);
    a[4] += __uint_as_float(v.z << 16); a[5] += __uint_as_float(v.z & 0xffff0000u);
    a[6] += __uint_as_float(v.w << 16); a[7] += __uint_as_float(v.w & 0xffff0000u);
  }
#pragma unroll
  for (int k = 0; k < 8; ++k) red[j * 33 + q * 8 + k] = a[k];
  __syncthreads();
  for (int off = 32; off >= 1; off >>= 1) {
    if (j < off) {
#pragma unroll
      for (int k = 0; k < 8; ++k)
        red[j * 33 + q * 8 + k] += red[(j + off) * 33 + q * 8 + k];
    }
    __syncthreads();
  }
  if (tid < 32) pool[g * 32 + tid] = red[tid] + (float)(end - start) * b3[tid];
}

// =================== MLP head ===================

__global__ void k_mlpz(const float* __restrict__ pool, const float* __restrict__ Wm0,
                       const float* __restrict__ bm0, float* __restrict__ z,
                       float* __restrict__ mstats) {
  __shared__ float Ws[32 * 32];
  __shared__ float ps[8 * 32];
  __shared__ float ls[TPB], lq[TPB];
  const int tid = threadIdx.x;
  const int g0 = blockIdx.x * 8;
  for (int k = tid; k < 1024; k += TPB) Ws[k] = Wm0[k];
  if (tid < 256) ps[tid] = pool[g0 * 32 + tid];
  __syncthreads();
  const int j = tid >> 5, c = tid & 31;
  float acc = bm0[c];
#pragma unroll
  for (int k = 0; k < 32; ++k) acc += ps[j * 32 + k] * Ws[k * 32 + c];
  z[(g0 + j) * 32 + c] = acc;
  ls[tid] = acc;
  lq[tid] = acc * acc;
  __syncthreads();
  for (int off = 128; off >= 32; off >>= 1) {
    if (tid < off) { ls[tid] += ls[tid + off]; lq[tid] += lq[tid + off]; }
    __syncthreads();
  }
  if (tid < 32) {
    unsafeAtomicAdd(&mstats[tid], ls[tid]);
    unsafeAtomicAdd(&mstats[32 + tid], lq[tid]);
  }
}

__global__ void k_mlpfin(const float* __restrict__ z, const float* __restrict__ mstats,
                         const float* __restrict__ bng, const float* __restrict__ bnb,
                         const float* __restrict__ Wm1, const float* __restrict__ bm1,
                         float* __restrict__ out) {
  __shared__ float sc[32], sh[32], w1[64];
  const int tid = threadIdx.x;
  if (tid < 32) {
    float m = mstats[tid] * (1.0f / 512.0f);
    float v = mstats[32 + tid] * (1.0f / 512.0f) - m * m;
    float s = bng[tid] * rsqrtf(v + EPSV);
    sc[tid] = s;
    sh[tid] = bnb[tid] - m * s;
  }
  if (tid < 64) w1[tid] = Wm1[tid];
  __syncthreads();
  const int g = tid >> 1, o = tid & 1;
  float acc = bm1[o];
#pragma unroll
  for (int c = 0; c < 32; ++c) {
    float hc = fmaxf(z[g * 32 + c] * sc[c] + sh[c], 0.f);
    acc += hc * w1[c * 2 + o];
  }
  out[tid] = acc;
}

// =================== launch ===================

extern "C" void kernel_launch(void* const* d_in, const int* in_sizes, int n_in,
                              void* d_out, int out_size, void* d_ws, size_t ws_size,
                              hipStream_t stream) {
  const float* x     = (const float*)d_in[0];
  const int*   ei    = (const int*)d_in[1];
  const float* ea    = (const float*)d_in[2];
  const int*   batch = (const int*)d_in[3];
  const float* W0    = (const float*)d_in[4];
  const float* W1    = (const float*)d_in[6];
  const float* W2    = (const float*)d_in[8];
  const float* W3    = (const float*)d_in[10];
  const float* b3    = (const float*)d_in[11];
  const float* bng   = (const float*)d_in[12];  // [3,32]
  const float* bnb   = (const float*)d_in[13];
  const float* Wm0   = (const float*)d_in[14];
  const float* bm0   = (const float*)d_in[15];
  const float* bnmg  = (const float*)d_in[16];
  const float* bnmb  = (const float*)d_in[17];
  const float* Wm1   = (const float*)d_in[18];
  const float* bm1   = (const float*)d_in[19];
  float* out = (float*)d_out;

  const int N = in_sizes[3];
  const int E = in_sizes[2];
  const int* row = ei;
  const int* col = ei + E;
  const int B = (N + RSZ - 1) >> RBITS;

  char* wsb = (char*)d_ws;
  auto alloc = [&](size_t bytes) { char* p = wsb; wsb += (bytes + 255) & ~size_t(255); return p; };
  int*   bcnt  = (int*)alloc((size_t)(BMAX + 1) * 4);
  int*   bbase = (int*)alloc((size_t)(BMAX + 1) * 4);
  int*   bcur  = (int*)alloc((size_t)BMAX * 4);
  int*   ptr   = (int*)alloc((size_t)(N + 1) * 4);
  uint2* buck  = (uint2*)alloc((size_t)E * 8);
  uint2* pk    = (uint2*)alloc((size_t)(E + 1) * 8);  // +1: prefetch slot
  float* dinv  = (float*)alloc((size_t)N * 4);
  uint4* G0    = (uint4*)alloc((size_t)N * 16);       // packed x (8 bf16)
  uint4* G1    = (uint4*)alloc((size_t)N * 16);       // A.x
  unsigned short* BA = (unsigned short*)alloc((size_t)N * 32 * 2);  // bf16 ping
  unsigned short* BB = (unsigned short*)alloc((size_t)N * 32 * 2);  // bf16 pong
  float* stats = (float*)alloc(4 * 64 * 4);
  float* pool  = (float*)alloc(512 * 32 * 4);
  float* zbuf  = (float*)alloc(512 * 32 * 4);

  hipMemsetAsync(bcnt, 0, (size_t)(BMAX + 1) * 4, stream);
  hipMemsetAsync(stats, 0, 4 * 64 * 4, stream);

  const int nb_c = (E + CHUNK - 1) / CHUNK;
  const int nb_t = (N + 31) / 32;
  const int nb_g = (N + 255) / 256;
  const int nquads = N * 4;
  const float invN = 1.0f / (float)N;
  float* mstats = stats + 192;

  // ---- CSR build (bucketed), packx fused into bcnt; nrme fused into gather0 ----
  k_bcnt<<<nb_c, TPB, 0, stream>>>(col, bcnt, x, G0, E, B, N);
  k_bscan<<<1, BMAX, 0, stream>>>(bcnt, bbase, bcur, B, E);
  k_binfill<<<nb_c, TPB, 0, stream>>>(row, col, ea, bcur, buck, E, B);
  k_bucket<<<B, 256, 0, stream>>>(buck, bbase, ptr, dinv, pk, N, E);

  // ---- layer 0: gather raw x (finalizes pk.y), then (A.x)@W0 ----
  k_gather0<<<nb_g, 256, 0, stream>>>(pk, ptr, dinv, G0, G1, N);
  k_transform0b<<<nb_t, 256, 0, stream>>>(G1, W0, (uint2*)BA, N);
  k_stats<<<1024, TPB, 0, stream>>>((const uint4*)BA, stats, nquads);

  // ---- layer 1 ----
  k_transform<<<nb_t, 256, 0, stream>>>((const uint4*)BA, W1, stats, bng, bnb, invN,
                                        (uint2*)BB, N);
  k_gather<<<nb_g, 256, 0, stream>>>(pk, ptr, dinv, (const uint4*)BB, (uint4*)BA, N);
  k_stats<<<1024, TPB, 0, stream>>>((const uint4*)BA, stats + 64, nquads);

  // ---- layer 2 ----
  k_transform<<<nb_t, 256, 0, stream>>>((const uint4*)BA, W2, stats + 64, bng + 32, bnb + 32,
                                        invN, (uint2*)BB, N);
  k_gather<<<nb_g, 256, 0, stream>>>(pk, ptr, dinv, (const uint4*)BB, (uint4*)BA, N);
  k_stats<<<1024, TPB, 0, stream>>>((const uint4*)BA, stats + 128, nquads);

  // ---- layer 3 (no BN on output) ----
  k_transform<<<nb_t, 256, 0, stream>>>((const uint4*)BA, W3, stats + 128, bng + 64, bnb + 64,
                                        invN, (uint2*)BB, N);
  k_gather<<<nb_g, 256, 0, stream>>>(pk, ptr, dinv, (const uint4*)BB, (uint4*)BA, N);

  // ---- pool + MLP head ----
  k_pool<<<512, 256, 0, stream>>>((const uint4*)BA, batch, b3, pool, N);
  k_mlpz<<<64, TPB, 0, stream>>>(pool, Wm0, bm0, zbuf, mstats);
  k_mlpfin<<<1, 1024, 0, stream>>>(zbuf, mstats, bnmg, bnmb, Wm1, bm1, out);
}

// Round 17
// 710.905 us; speedup vs baseline: 6.3397x; 1.0474x over previous
//
#include <hip/hip_runtime.h>

#define TPB 256
#define RBITS 10               // bucket = node >> 10 (1024 nodes/bucket)
#define RSZ   1024
#define BMAX  512              // max buckets supported (N <= 512K)
#define CHUNK 4096             // edges per block in bucket passes
constexpr float EPSV = 1e-5f;

__device__ __forceinline__ float bf2f(unsigned short u) {
  return __uint_as_float((unsigned)u << 16);
}
__device__ __forceinline__ unsigned short f2bf(float f) {
  unsigned u = __float_as_uint(f);
  return (unsigned short)((u + 0x7fffu + ((u >> 16) & 1u)) >> 16);  // RNE
}

// =================== bucket-sorted CSR build (packx fused into bcnt) ===================

__global__ void k_bcnt(const int* __restrict__ col, int* __restrict__ bcnt,
                       const float* __restrict__ x, uint4* __restrict__ g,
                       int E, int B, int N) {
  __shared__ int h[BMAX];
  const int tid = threadIdx.x;
  for (int i = tid; i < B; i += TPB) h[i] = 0;
  __syncthreads();
  const int e0 = blockIdx.x * CHUNK;
  for (int k = tid; k < CHUNK; k += TPB) {
    int i = e0 + k;
    if (i < E) atomicAdd(&h[col[i] >> RBITS], 1);
  }
  __syncthreads();
  for (int i = tid; i < B; i += TPB)
    if (h[i]) atomicAdd(&bcnt[i], h[i]);
  // fused packx (independent work, grid-stride)
  for (int n = blockIdx.x * TPB + tid; n < N; n += gridDim.x * TPB) {
    const float* p = x + (size_t)n * 7;
    unsigned b[8];
#pragma unroll
    for (int k = 0; k < 7; ++k) b[k] = f2bf(p[k]);
    b[7] = 0;
    uint4 o;
    o.x = b[0] | (b[1] << 16); o.y = b[2] | (b[3] << 16);
    o.z = b[4] | (b[5] << 16); o.w = b[6] | (b[7] << 16);
    g[n] = o;
  }
}

__global__ void k_bscan(const int* __restrict__ bcnt, int* __restrict__ bbase,
                        int* __restrict__ bcur, int B, int E) {
  __shared__ int red[BMAX];
  const int tid = threadIdx.x;  // 512 threads
  int v = (tid < B) ? bcnt[tid] : 0;
  red[tid] = v;
  __syncthreads();
  for (int off = 1; off < BMAX; off <<= 1) {
    int u = (tid >= off) ? red[tid - off] : 0;
    __syncthreads();
    red[tid] += u;
    __syncthreads();
  }
  int excl = red[tid] - v;
  if (tid < B) { bbase[tid] = excl; bcur[tid] = excl; }
  if (tid == 0) bbase[B] = E;
}

__global__ void k_binfill(const int* __restrict__ row, const int* __restrict__ col,
                          const float* __restrict__ w, int* __restrict__ bcur,
                          uint2* __restrict__ buck, int E, int B) {
  __shared__ int h[BMAX], base[BMAX], cur[BMAX];
  const int tid = threadIdx.x;
  for (int i = tid; i < B; i += TPB) { h[i] = 0; cur[i] = 0; }
  __syncthreads();
  const int e0 = blockIdx.x * CHUNK;
  for (int k = tid; k < CHUNK; k += TPB) {
    int i = e0 + k;
    if (i < E) atomicAdd(&h[col[i] >> RBITS], 1);
  }
  __syncthreads();
  for (int i = tid; i < B; i += TPB)
    base[i] = h[i] ? atomicAdd(&bcur[i], h[i]) : 0;
  __syncthreads();
  for (int k = tid; k < CHUNK; k += TPB) {
    int i = e0 + k;
    if (i >= E) continue;
    int c = col[i];
    int b = c >> RBITS;
    int pos = base[b] + atomicAdd(&cur[b], 1);
    unsigned lc = (unsigned)(c & (RSZ - 1));
    buck[pos] = make_uint2((unsigned)row[i] | (lc << 19), __float_as_uint(w[i]));
  }
}

// per-bucket counting sort -> CSR; pk.y pre-multiplied by dinv[col] (local!)
__global__ __launch_bounds__(256) void k_bucket(const uint2* __restrict__ buck,
                                                const int* __restrict__ bbase,
                                                int* __restrict__ ptr, float* __restrict__ dinv,
                                                uint2* __restrict__ pk, int N, int E) {
  __shared__ int cnt[RSZ];
  __shared__ float wsum[RSZ];
  __shared__ int lofs[RSZ];
  __shared__ int red[256];
  const int bk = blockIdx.x, tid = threadIdx.x;
  const int n0 = bk << RBITS;
  const int nloc = min(RSZ, N - n0);
  for (int i = tid; i < RSZ; i += 256) { cnt[i] = 0; wsum[i] = 0.f; }
  __syncthreads();
  const int e0 = bbase[bk], e1 = bbase[bk + 1];
  for (int i = e0 + tid; i < e1; i += 256) {
    uint2 e = buck[i];
    int lc = e.x >> 19;
    atomicAdd(&cnt[lc], 1);
    atomicAdd(&wsum[lc], __uint_as_float(e.y));
  }
  __syncthreads();
  int a = cnt[tid * 4], b = cnt[tid * 4 + 1], c = cnt[tid * 4 + 2], d = cnt[tid * 4 + 3];
  int l1 = a, l2 = a + b, l3 = a + b + c, s = a + b + c + d;
  red[tid] = s;
  __syncthreads();
  for (int off = 1; off < 256; off <<= 1) {
    int u = (tid >= off) ? red[tid - off] : 0;
    __syncthreads();
    red[tid] += u;
    __syncthreads();
  }
  int tb = red[tid] - s;
  lofs[tid * 4] = tb; lofs[tid * 4 + 1] = tb + l1;
  lofs[tid * 4 + 2] = tb + l2; lofs[tid * 4 + 3] = tb + l3;
  __syncthreads();
  for (int i = tid; i < nloc; i += 256) {
    ptr[n0 + i] = e0 + lofs[i];
    dinv[n0 + i] = rsqrtf(1.0f + wsum[i]);  // deg >= 1 (self-loop)
  }
  for (int i = tid; i < RSZ; i += 256) cnt[i] = 0;
  __syncthreads();
  for (int i = e0 + tid; i < e1; i += 256) {
    uint2 e = buck[i];
    int lc = e.x >> 19;
    int pos = e0 + lofs[lc] + atomicAdd(&cnt[lc], 1);
    float wdc = __uint_as_float(e.y) * rsqrtf(1.0f + wsum[lc]);  // w * dinv[col]
    pk[pos] = make_uint2(e.x & 524287u, __float_as_uint(wdc));
  }
  if (bk == 0 && tid == 0) ptr[N] = E;
}

// finish norm edge-parallel: pk.y *= dinv[row] (separate pass — fusing this
// into the gather loop (r16) cost +25 us from partial-line write amplification)
__global__ void k_nrme(uint2* __restrict__ pk, const float* __restrict__ dinv, int E) {
  int e = blockIdx.x * blockDim.x + threadIdx.x;
  if (e < E) {
    uint2 v = pk[e];
    pk[e].y = __float_as_uint(__uint_as_float(v.y) * dinv[v.x]);
  }
}

// =================== layer-0 transform: BA = G1 @ W0 (7 eff. channels) ===================

__global__ __launch_bounds__(256) void k_transform0b(
    const uint4* __restrict__ g1, const float* __restrict__ W,
    uint2* __restrict__ t2, int N) {
  __shared__ float Ws[7 * 32];
  __shared__ float hs[32 * 9];
  const int tid = threadIdx.x;
  const int n0 = blockIdx.x * 32;
  if (tid < 224) Ws[tid] = W[tid];
  if (tid < 32) {
    const int node = n0 + tid;
    uint4 v = make_uint4(0, 0, 0, 0);
    if (node < N) v = g1[node];
    float* h = &hs[tid * 9];
    h[0] = __uint_as_float(v.x << 16); h[1] = __uint_as_float(v.x & 0xffff0000u);
    h[2] = __uint_as_float(v.y << 16); h[3] = __uint_as_float(v.y & 0xffff0000u);
    h[4] = __uint_as_float(v.z << 16); h[5] = __uint_as_float(v.z & 0xffff0000u);
    h[6] = __uint_as_float(v.w << 16); h[7] = 0.f;
  }
  __syncthreads();
  const int j = tid >> 3, q = tid & 7, c0 = q * 4;
  const int node = n0 + j;
  if (node < N) {
    float a0 = 0.f, a1 = 0.f, a2 = 0.f, a3 = 0.f;
#pragma unroll
    for (int k = 0; k < 7; ++k) {
      float v = hs[j * 9 + k];
      const float* w = &Ws[k * 32 + c0];
      a0 += v * w[0]; a1 += v * w[1]; a2 += v * w[2]; a3 += v * w[3];
    }
    uint2 o;
    o.x = (unsigned)f2bf(a0) | ((unsigned)f2bf(a1) << 16);
    o.y = (unsigned)f2bf(a2) | ((unsigned)f2bf(a3) << 16);
    t2[(size_t)node * 8 + q] = o;
  }
}

// =================== transforms layers 1-3 ===================

__global__ __launch_bounds__(256) void k_transform(
    const uint4* __restrict__ in4, const float* __restrict__ W,
    const float* __restrict__ gstats, const float* __restrict__ gamma,
    const float* __restrict__ beta, float invN, uint2* __restrict__ t2, int N) {
  __shared__ float Ws[1024];
  __shared__ float hs[32 * 33];
  __shared__ float ssb[64];
  const int tid = threadIdx.x;
  const int n0 = blockIdx.x * 32;
#pragma unroll
  for (int k = 0; k < 4; ++k) Ws[k * 256 + tid] = W[k * 256 + tid];
  if (tid < 32) {
    float m = gstats[tid] * invN;
    float v = gstats[32 + tid] * invN - m * m;
    float sc = gamma[tid] * rsqrtf(v + EPSV);
    ssb[tid] = sc;
    ssb[32 + tid] = beta[tid] - m * sc;
  }
  __syncthreads();
  if (tid < 128) {
    const int r = tid >> 2, q = tid & 3;
    const int node = n0 + r;
    uint4 v = make_uint4(0, 0, 0, 0);
    if (node < N) v = in4[(size_t)node * 4 + q];
    float* h = &hs[r * 33 + q * 8];
    const float* sc = &ssb[q * 8];
    const float* sh = &ssb[32 + q * 8];
    h[0] = fmaxf(__uint_as_float(v.x << 16) * sc[0] + sh[0], 0.f);
    h[1] = fmaxf(__uint_as_float(v.x & 0xffff0000u) * sc[1] + sh[1], 0.f);
    h[2] = fmaxf(__uint_as_float(v.y << 16) * sc[2] + sh[2], 0.f);
    h[3] = fmaxf(__uint_as_float(v.y & 0xffff0000u) * sc[3] + sh[3], 0.f);
    h[4] = fmaxf(__uint_as_float(v.z << 16) * sc[4] + sh[4], 0.f);
    h[5] = fmaxf(__uint_as_float(v.z & 0xffff0000u) * sc[5] + sh[5], 0.f);
    h[6] = fmaxf(__uint_as_float(v.w << 16) * sc[6] + sh[6], 0.f);
    h[7] = fmaxf(__uint_as_float(v.w & 0xffff0000u) * sc[7] + sh[7], 0.f);
  }
  __syncthreads();
  const int j = tid >> 3;
  const int c0 = (tid & 7) * 4;
  const int node = n0 + j;
  if (node < N) {
    float a0 = 0.f, a1 = 0.f, a2 = 0.f, a3 = 0.f;
#pragma unroll
    for (int k = 0; k < 32; ++k) {
      float v = hs[j * 33 + k];
      const float* w = &Ws[k * 32 + c0];
      a0 += v * w[0]; a1 += v * w[1]; a2 += v * w[2]; a3 += v * w[3];
    }
    uint2 o;
    o.x = (unsigned)f2bf(a0) | ((unsigned)f2bf(a1) << 16);
    o.y = (unsigned)f2bf(a2) | ((unsigned)f2bf(a3) << 16);
    t2[(size_t)node * 8 + (tid & 7)] = o;
  }
}

// =================== CSR gather: lane-per-node, templated row width ===================
// Pristine read-only loop: 64 independent rows in flight/wave, pk prefetch.
// (r13-verified: ~69 us, 3.3 TB/s, FETCH within ~6% of line-granule minimum.)

__device__ __forceinline__ void fma8(float* acc, uint4 v, float wt) {
  acc[0] += wt * __uint_as_float(v.x << 16);
  acc[1] += wt * __uint_as_float(v.x & 0xffff0000u);
  acc[2] += wt * __uint_as_float(v.y << 16);
  acc[3] += wt * __uint_as_float(v.y & 0xffff0000u);
  acc[4] += wt * __uint_as_float(v.z << 16);
  acc[5] += wt * __uint_as_float(v.z & 0xffff0000u);
  acc[6] += wt * __uint_as_float(v.w << 16);
  acc[7] += wt * __uint_as_float(v.w & 0xffff0000u);
}

template <int Q>
__global__ __launch_bounds__(256, 4) void k_gather(
    const uint2* __restrict__ pk, const int* __restrict__ ptr,
    const float* __restrict__ dinv, const uint4* __restrict__ t4,
    uint4* __restrict__ out4, int N) {
  const int n = blockIdx.x * 256 + threadIdx.x;
  if (n >= N) return;
  const int p0 = ptr[n], p1 = ptr[n + 1];
  const float dvn = dinv[n];
  float acc[8 * Q];
#pragma unroll
  for (int k = 0; k < 8 * Q; ++k) acc[k] = 0.f;
  {
    const float wt = dvn * dvn;
    const size_t rb = (size_t)n * Q;
#pragma unroll
    for (int qq = 0; qq < Q; ++qq) fma8(acc + 8 * qq, t4[rb + qq], wt);
  }
  if (p0 < p1) {
    uint2 e = pk[p0];
    for (int p = p0; p < p1; ++p) {
      uint2 en = pk[p + 1];  // prefetch (pk allocated E+1)
      const float wt = __uint_as_float(e.y);
      const size_t rb = (size_t)e.x * Q;
#pragma unroll
      for (int qq = 0; qq < Q; ++qq) fma8(acc + 8 * qq, t4[rb + qq], wt);
      e = en;
    }
  }
  const size_t ob = (size_t)n * Q;
#pragma unroll
  for (int qq = 0; qq < Q; ++qq) {
    uint4 o;
    o.x = (unsigned)f2bf(acc[qq * 8 + 0]) | ((unsigned)f2bf(acc[qq * 8 + 1]) << 16);
    o.y = (unsigned)f2bf(acc[qq * 8 + 2]) | ((unsigned)f2bf(acc[qq * 8 + 3]) << 16);
    o.z = (unsigned)f2bf(acc[qq * 8 + 4]) | ((unsigned)f2bf(acc[qq * 8 + 5]) << 16);
    o.w = (unsigned)f2bf(acc[qq * 8 + 6]) | ((unsigned)f2bf(acc[qq * 8 + 7]) << 16);
    out4[ob + qq] = o;
  }
}

// =================== BN stats, vectorized (uint4 = 8 bf16 per load) ===================

__global__ void k_stats(const uint4* __restrict__ x4, float* __restrict__ gstats, int nquads) {
  __shared__ float ls[64];
  const int tid = threadIdx.x;
  if (tid < 64) ls[tid] = 0.f;
  __syncthreads();
  const int q = tid & 3;
  float s[8], sq[8];
#pragma unroll
  for (int k = 0; k < 8; ++k) { s[k] = 0.f; sq[k] = 0.f; }
  for (int idx = blockIdx.x * TPB + tid; idx < nquads; idx += gridDim.x * TPB) {
    uint4 v = x4[idx];
    float f0 = __uint_as_float(v.x << 16), f1 = __uint_as_float(v.x & 0xffff0000u);
    float f2 = __uint_as_float(v.y << 16), f3 = __uint_as_float(v.y & 0xffff0000u);
    float f4 = __uint_as_float(v.z << 16), f5 = __uint_as_float(v.z & 0xffff0000u);
    float f6 = __uint_as_float(v.w << 16), f7 = __uint_as_float(v.w & 0xffff0000u);
    s[0] += f0; sq[0] += f0 * f0;  s[1] += f1; sq[1] += f1 * f1;
    s[2] += f2; sq[2] += f2 * f2;  s[3] += f3; sq[3] += f3 * f3;
    s[4] += f4; sq[4] += f4 * f4;  s[5] += f5; sq[5] += f5 * f5;
    s[6] += f6; sq[6] += f6 * f6;  s[7] += f7; sq[7] += f7 * f7;
  }
#pragma unroll
  for (int k = 0; k < 8; ++k) {
    int c = q * 8 + k;
    atomicAdd(&ls[c], s[k]);
    atomicAdd(&ls[32 + c], sq[k]);
  }
  __syncthreads();
  if (tid < 64) unsafeAtomicAdd(&gstats[tid], ls[tid]);
}

// =================== global add pool (batch sorted, uint4 loads) ===================

__global__ __launch_bounds__(256) void k_pool(
    const uint4* __restrict__ h4, const int* __restrict__ batch,
    const float* __restrict__ b3, float* __restrict__ pool, int N) {
  __shared__ float red[64 * 33];
  const int g = blockIdx.x, tid = threadIdx.x;
  int lo = 0, hi = N;
  while (lo < hi) { int mid = (lo + hi) >> 1; if (batch[mid] < g) lo = mid + 1; else hi = mid; }
  const int start = lo;
  hi = N;
  while (lo < hi) { int mid = (lo + hi) >> 1; if (batch[mid] < g + 1) lo = mid + 1; else hi = mid; }
  const int end = lo;
  const int j = tid >> 2, q = tid & 3;
  float a[8];
#pragma unroll
  for (int k = 0; k < 8; ++k) a[k] = 0.f;
  for (int i = start + j; i < end; i += 64) {
    uint4 v = h4[(size_t)i * 4 + q];
    a[0] += __uint_as_float(v.x << 16); a[1] += __uint_as_float(v.x & 0xffff0000u);
    a[2] += __uint_as_float(v.y << 16); a[3] += __uint_as_float(v.y & 0xffff0000u);
    a[4] += __uint_as_float(v.z << 16); a[5] += __uint_as_float(v.z & 0xffff0000u);
    a[6] += __uint_as_float(v.w << 16); a[7] += __uint_as_float(v.w & 0xffff0000u);
  }
#pragma unroll
  for (int k = 0; k < 8; ++k) red[j * 33 + q * 8 + k] = a[k];
  __syncthreads();
  for (int off = 32; off >= 1; off >>= 1) {
    if (j < off) {
#pragma unroll
      for (int k = 0; k < 8; ++k)
        red[j * 33 + q * 8 + k] += red[(j + off) * 33 + q * 8 + k];
    }
    __syncthreads();
  }
  if (tid < 32) pool[g * 32 + tid] = red[tid] + (float)(end - start) * b3[tid];
}

// =================== MLP head ===================

__global__ void k_mlpz(const float* __restrict__ pool, const float* __restrict__ Wm0,
                       const float* __restrict__ bm0, float* __restrict__ z,
                       float* __restrict__ mstats) {
  __shared__ float Ws[32 * 32];
  __shared__ float ps[8 * 32];
  __shared__ float ls[TPB], lq[TPB];
  const int tid = threadIdx.x;
  const int g0 = blockIdx.x * 8;
  for (int k = tid; k < 1024; k += TPB) Ws[k] = Wm0[k];
  if (tid < 256) ps[tid] = pool[g0 * 32 + tid];
  __syncthreads();
  const int j = tid >> 5, c = tid & 31;
  float acc = bm0[c];
#pragma unroll
  for (int k = 0; k < 32; ++k) acc += ps[j * 32 + k] * Ws[k * 32 + c];
  z[(g0 + j) * 32 + c] = acc;
  ls[tid] = acc;
  lq[tid] = acc * acc;
  __syncthreads();
  for (int off = 128; off >= 32; off >>= 1) {
    if (tid < off) { ls[tid] += ls[tid + off]; lq[tid] += lq[tid + off]; }
    __syncthreads();
  }
  if (tid < 32) {
    unsafeAtomicAdd(&mstats[tid], ls[tid]);
    unsafeAtomicAdd(&mstats[32 + tid], lq[tid]);
  }
}

__global__ void k_mlpfin(const float* __restrict__ z, const float* __restrict__ mstats,
                         const float* __restrict__ bng, const float* __restrict__ bnb,
                         const float* __restrict__ Wm1, const float* __restrict__ bm1,
                         float* __restrict__ out) {
  __shared__ float sc[32], sh[32], w1[64];
  const int tid = threadIdx.x;
  if (tid < 32) {
    float m = mstats[tid] * (1.0f / 512.0f);
    float v = mstats[32 + tid] * (1.0f / 512.0f) - m * m;
    float s = bng[tid] * rsqrtf(v + EPSV);
    sc[tid] = s;
    sh[tid] = bnb[tid] - m * s;
  }
  if (tid < 64) w1[tid] = Wm1[tid];
  __syncthreads();
  const int g = tid >> 1, o = tid & 1;
  float acc = bm1[o];
#pragma unroll
  for (int c = 0; c < 32; ++c) {
    float hc = fmaxf(z[g * 32 + c] * sc[c] + sh[c], 0.f);
    acc += hc * w1[c * 2 + o];
  }
  out[tid] = acc;
}

// =================== launch ===================

extern "C" void kernel_launch(void* const* d_in, const int* in_sizes, int n_in,
                              void* d_out, int out_size, void* d_ws, size_t ws_size,
                              hipStream_t stream) {
  const float* x     = (const float*)d_in[0];
  const int*   ei    = (const int*)d_in[1];
  const float* ea    = (const float*)d_in[2];
  const int*   batch = (const int*)d_in[3];
  const float* W0    = (const float*)d_in[4];
  const float* W1    = (const float*)d_in[6];
  const float* W2    = (const float*)d_in[8];
  const float* W3    = (const float*)d_in[10];
  const float* b3    = (const float*)d_in[11];
  const float* bng   = (const float*)d_in[12];  // [3,32]
  const float* bnb   = (const float*)d_in[13];
  const float* Wm0   = (const float*)d_in[14];
  const float* bm0   = (const float*)d_in[15];
  const float* bnmg  = (const float*)d_in[16];
  const float* bnmb  = (const float*)d_in[17];
  const float* Wm1   = (const float*)d_in[18];
  const float* bm1   = (const float*)d_in[19];
  float* out = (float*)d_out;

  const int N = in_sizes[3];
  const int E = in_sizes[2];
  const int* row = ei;
  const int* col = ei + E;
  const int B = (N + RSZ - 1) >> RBITS;

  char* wsb = (char*)d_ws;
  auto alloc = [&](size_t bytes) { char* p = wsb; wsb += (bytes + 255) & ~size_t(255); return p; };
  int*   bcnt  = (int*)alloc((size_t)(BMAX + 1) * 4);
  int*   bbase = (int*)alloc((size_t)(BMAX + 1) * 4);
  int*   bcur  = (int*)alloc((size_t)BMAX * 4);
  int*   ptr   = (int*)alloc((size_t)(N + 1) * 4);
  uint2* buck  = (uint2*)alloc((size_t)E * 8);
  uint2* pk    = (uint2*)alloc((size_t)(E + 1) * 8);  // +1: prefetch slot
  float* dinv  = (float*)alloc((size_t)N * 4);
  uint4* G0    = (uint4*)alloc((size_t)N * 16);       // packed x (8 bf16)
  uint4* G1    = (uint4*)alloc((size_t)N * 16);       // A.x
  unsigned short* BA = (unsigned short*)alloc((size_t)N * 32 * 2);  // bf16 ping
  unsigned short* BB = (unsigned short*)alloc((size_t)N * 32 * 2);  // bf16 pong
  float* stats = (float*)alloc(4 * 64 * 4);
  float* pool  = (float*)alloc(512 * 32 * 4);
  float* zbuf  = (float*)alloc(512 * 32 * 4);

  hipMemsetAsync(bcnt, 0, (size_t)(BMAX + 1) * 4, stream);
  hipMemsetAsync(stats, 0, 4 * 64 * 4, stream);

  const int nb_c = (E + CHUNK - 1) / CHUNK;
  const int nb_e = (E + 255) / 256;
  const int nb_t = (N + 31) / 32;
  const int nb_g = (N + 255) / 256;
  const int nquads = N * 4;
  const float invN = 1.0f / (float)N;
  float* mstats = stats + 192;

  // ---- CSR build (bucketed), packx fused into bcnt ----
  k_bcnt<<<nb_c, TPB, 0, stream>>>(col, bcnt, x, G0, E, B, N);
  k_bscan<<<1, BMAX, 0, stream>>>(bcnt, bbase, bcur, B, E);
  k_binfill<<<nb_c, TPB, 0, stream>>>(row, col, ea, bcur, buck, E, B);
  k_bucket<<<B, 256, 0, stream>>>(buck, bbase, ptr, dinv, pk, N, E);
  k_nrme<<<nb_e, 256, 0, stream>>>(pk, dinv, E);

  // ---- layer 0: gather raw x (16 B rows, L2-hot), then (A.x)@W0 ----
  k_gather<1><<<nb_g, 256, 0, stream>>>(pk, ptr, dinv, G0, G1, N);
  k_transform0b<<<nb_t, 256, 0, stream>>>(G1, W0, (uint2*)BA, N);
  k_stats<<<1024, TPB, 0, stream>>>((const uint4*)BA, stats, nquads);

  // ---- layer 1 ----
  k_transform<<<nb_t, 256, 0, stream>>>((const uint4*)BA, W1, stats, bng, bnb, invN,
                                        (uint2*)BB, N);
  k_gather<4><<<nb_g, 256, 0, stream>>>(pk, ptr, dinv, (const uint4*)BB, (uint4*)BA, N);
  k_stats<<<1024, TPB, 0, stream>>>((const uint4*)BA, stats + 64, nquads);

  // ---- layer 2 ----
  k_transform<<<nb_t, 256, 0, stream>>>((const uint4*)BA, W2, stats + 64, bng + 32, bnb + 32,
                                        invN, (uint2*)BB, N);
  k_gather<4><<<nb_g, 256, 0, stream>>>(pk, ptr, dinv, (const uint4*)BB, (uint4*)BA, N);
  k_stats<<<1024, TPB, 0, stream>>>((const uint4*)BA, stats + 128, nquads);

  // ---- layer 3 (no BN on output) ----
  k_transform<<<nb_t, 256, 0, stream>>>((const uint4*)BA, W3, stats + 128, bng + 64, bnb + 64,
                                        invN, (uint2*)BB, N);
  k_gather<4><<<nb_g, 256, 0, stream>>>(pk, ptr, dinv, (const uint4*)BB, (uint4*)BA, N);

  // ---- pool + MLP head ----
  k_pool<<<512, 256, 0, stream>>>((const uint4*)BA, batch, b3, pool, N);
  k_mlpz<<<64, TPB, 0, stream>>>(pool, Wm0, bm0, zbuf, mstats);
  k_mlpfin<<<1, 1024, 0, stream>>>(zbuf, mstats, bnmg, bnmb, Wm1, bm1, out);
}